// Round 4
// baseline (791.025 us; speedup 1.0000x reference)
//
#include <hip/hip_runtime.h>

#define BS 128
#define T 256
#define D 1024
#define NCAT 2688
#define NFEAT 1024

typedef short bf16x8 __attribute__((ext_vector_type(8)));
typedef float f32x4 __attribute__((ext_vector_type(4)));
typedef unsigned short u16;
typedef u16 u16x4 __attribute__((ext_vector_type(4)));

__device__ __forceinline__ u16 f2bf(float f) {
    unsigned int u = __float_as_uint(f);
    u += 0x7fffu + ((u >> 16) & 1u);   // round-to-nearest-even
    return (u16)(u >> 16);
}

// control block indices (ints at start of ws, memset to 0 each call)
#define C_BATCH 0     // [0..127]  per-batch chunk counters
#define C_GRP   128   // [128..135] batches finalized per group of 16
#define C_W12   136   // W1b/W2b convert blocks done (1024)
#define C_W4    137   // W4b convert blocks done (2688)
#define C_K3MT  144   // [144..151] k3 blocks done per m-tile (16 each)

__device__ __forceinline__ void wait2(int* p1, int t1, int* p2, int t2) {
    if (threadIdx.x == 0) {
        while (__hip_atomic_load(p1, __ATOMIC_ACQUIRE, __HIP_MEMORY_SCOPE_AGENT) < t1 ||
               __hip_atomic_load(p2, __ATOMIC_ACQUIRE, __HIP_MEMORY_SCOPE_AGENT) < t2)
            __builtin_amdgcn_s_sleep(8);
    }
    __syncthreads();
}

// ---------------------------------------------------------------------------
// Mega-kernel. Roles by blockIdx.x:
//  [0,1024)      copy visual_fea + pooling partials; last chunk block of each
//                batch finalizes (gv/lv -> cat, sen -> cat+out1, loc head)
//  [1024,2048)   W1,W2 f32->bf16
//  [2048,4736)   W4 f32->bf16
//  [4736,4864)   k3: vs = relu((lv@W1^T+b1)*(sen@W2^T+b2)) -> cat  (gated)
//  [4864,5376)   k4: feature = relu(cat@W4^T+b4) -> out2           (gated)
// cat layout: [sen 0..1023 | gv 1024..2047 | vs 2048..2559 | loc 2560..2687]
// ---------------------------------------------------------------------------
__global__ __launch_bounds__(256, 4)
void mega(const float* __restrict__ vf, float* __restrict__ out0,
          const int* __restrict__ vmask, const float* __restrict__ loc,
          const float* __restrict__ sen_fea,
          const float* __restrict__ W1, const float* __restrict__ W2,
          const float* __restrict__ W3, const float* __restrict__ W4,
          const float* __restrict__ b1, const float* __restrict__ b2,
          const float* __restrict__ b3, const float* __restrict__ b4,
          u16* __restrict__ W1b, u16* __restrict__ W2b, u16* __restrict__ W4b,
          float* __restrict__ pgv, float* __restrict__ pseg,
          u16* __restrict__ cat, u16* __restrict__ lv,
          float* __restrict__ out1, float* __restrict__ out2,
          int* __restrict__ ctl) {
    int blk = blockIdx.x, tid = threadIdx.x;

    __shared__ int   red[256];
    __shared__ int   sse[3];
    __shared__ int   lastf;
    __shared__ float qsf[3][4][64];

    if (blk < 1024) {
        // ---------------- copy + pool + (maybe) finalize ----------------
        int b = blk >> 3, tc = blk & 7;
        red[tid] = vmask[b * T + tid];
        __syncthreads();
        for (int off = 128; off > 0; off >>= 1) {
            if (tid < off) red[tid] += red[tid + off];
            __syncthreads();
        }
        if (tid == 0) {
            int vl = red[0];
            float sc = (float)(vl - 1);
            sse[0] = vl;
            sse[1] = (int)floorf(loc[2 * b] * sc);
            sse[2] = (int)floorf(loc[2 * b + 1] * sc);
        }
        __syncthreads();
        int vl = sse[0], s = sse[1], e = sse[2];

        int d0 = tid * 4;
        f32x4 g  = {0.f, 0.f, 0.f, 0.f};
        f32x4 sg = {0.f, 0.f, 0.f, 0.f};
        const float* src = vf   + ((size_t)(b * T + tc * 32)) * D + d0;
        float*       dst = out0 + ((size_t)(b * T + tc * 32)) * D + d0;
        for (int i = 0; i < 32; ++i) {
            f32x4 v = *(const f32x4*)src;
            __builtin_nontemporal_store(v, (f32x4*)dst);
            int t = tc * 32 + i;
            if (t < vl) g += v;
            if (t >= s && t <= e) sg += v;
            src += D; dst += D;
        }
        int o = (b * 8 + tc) * D + d0;
        *(f32x4*)(pgv  + o) = g;
        *(f32x4*)(pseg + o) = sg;

        __threadfence();
        __syncthreads();
        if (tid == 0) {
            int old = __hip_atomic_fetch_add(&ctl[C_BATCH + b], 1,
                                             __ATOMIC_ACQ_REL, __HIP_MEMORY_SCOPE_AGENT);
            lastf = (old == 7);
        }
        __syncthreads();
        if (!lastf) return;

        // -------- finalize batch b (deterministic fixed-order reduce) --------
        float inv_vl = 1.0f / (float)vl;
        int cnt = e + 1 - s; if (cnt < 1) cnt = 1;
        float inv_cnt = 1.0f / (float)cnt;
        bool valid = (s <= e);
        for (int d = tid; d < D; d += 256) {
            float gs = 0.f, ss = 0.f;
#pragma unroll
            for (int c = 0; c < 8; ++c) {
                gs += pgv [(b * 8 + c) * D + d];
                ss += pseg[(b * 8 + c) * D + d];
            }
            cat[b * NCAT + 1024 + d] = f2bf(gs * inv_vl);
            lv[b * D + d] = f2bf(valid ? ss * inv_cnt : 0.f);
            float sf = sen_fea[b * D + d];
            cat[b * NCAT + d] = f2bf(sf);
            out1[b * D + d] = sf;
        }
        if (tid < 128) {
            float v = loc[2 * b] * W3[2 * tid] + loc[2 * b + 1] * W3[2 * tid + 1] + b3[tid];
            cat[b * NCAT + 2560 + tid] = f2bf(fmaxf(v, 0.f));
        }
        __threadfence();
        __syncthreads();
        if (tid == 0)
            __hip_atomic_fetch_add(&ctl[C_GRP + (b >> 4)], 1,
                                   __ATOMIC_RELEASE, __HIP_MEMORY_SCOPE_AGENT);
        return;
    }

    if (blk < 2048) {
        // ---------------- convert W1, W2 ----------------
        int i = (blk - 1024) * 256 + tid;    // float4 index in [0, 262144)
        const float* src; u16* dst;
        if (i < 131072) { src = W1 + 4 * i;            dst = W1b + 4 * i; }
        else            { src = W2 + 4 * (i - 131072); dst = W2b + 4 * (i - 131072); }
        f32x4 v = *(const f32x4*)src;
        u16x4 oo;
#pragma unroll
        for (int j = 0; j < 4; ++j) oo[j] = f2bf(v[j]);
        *(u16x4*)dst = oo;
        __threadfence();
        __syncthreads();
        if (tid == 0)
            __hip_atomic_fetch_add(&ctl[C_W12], 1, __ATOMIC_RELEASE, __HIP_MEMORY_SCOPE_AGENT);
        return;
    }

    if (blk < 4736) {
        // ---------------- convert W4 ----------------
        int i = (blk - 2048) * 256 + tid;    // float4 index in [0, 688128)
        f32x4 v = *(const f32x4*)(W4 + 4 * i);
        u16x4 oo;
#pragma unroll
        for (int j = 0; j < 4; ++j) oo[j] = f2bf(v[j]);
        *(u16x4*)(W4b + 4 * i) = oo;
        __threadfence();
        __syncthreads();
        if (tid == 0)
            __hip_atomic_fetch_add(&ctl[C_W4], 1, __ATOMIC_RELEASE, __HIP_MEMORY_SCOPE_AGENT);
        return;
    }

    if (blk < 4864) {
        // ---------------- k3: vs GEMMs ----------------
        int bi = blk - 4736;                 // [0,128)
        int mt = bi >> 4, ntg = bi & 15;
        wait2(&ctl[C_GRP + mt], 16, &ctl[C_W12], 1024);

        int wid = tid >> 6, lane = tid & 63;
        int chain = wid & 1, sub = wid >> 1;
        int m0 = mt * 16, n0 = ntg * 32 + sub * 16;
        int row = lane & 15, kg = lane >> 4;

        const u16* pa = chain ? (cat + (m0 + row) * NCAT + kg * 8)      // sen cols
                              : (lv  + (m0 + row) * D    + kg * 8);
        const u16* pb = (chain ? W2b : W1b) + (n0 + row) * D + kg * 8;

        f32x4 acc = {0.f, 0.f, 0.f, 0.f};
        for (int k = 0; k < 1024; k += 32)
            acc = __builtin_amdgcn_mfma_f32_16x16x32_bf16(*(const bf16x8*)(pa + k),
                                                          *(const bf16x8*)(pb + k), acc, 0, 0, 0);
        int col = lane & 15, rbase = (lane >> 4) * 4;
        float bb = (chain ? b2 : b1)[n0 + col];
        if (chain) {
#pragma unroll
            for (int r = 0; r < 4; ++r) qsf[sub][r][lane] = acc[r] + bb;
        }
        __syncthreads();
        if (!chain) {
#pragma unroll
            for (int r = 0; r < 4; ++r) {
                float p = acc[r] + bb;
                cat[(m0 + rbase + r) * NCAT + 2048 + n0 + col] =
                    f2bf(fmaxf(p * qsf[sub][r][lane], 0.f));
            }
        }
        __threadfence();
        __syncthreads();
        if (tid == 0)
            __hip_atomic_fetch_add(&ctl[C_K3MT + mt], 1,
                                   __ATOMIC_RELEASE, __HIP_MEMORY_SCOPE_AGENT);
        return;
    }

    {
        // ---------------- k4: feature GEMM (split-K=4) ----------------
        int bi = blk - 4864;                 // [0,512)
        int mt = bi >> 6, nt = bi & 63;
        wait2(&ctl[C_K3MT + mt], 16, &ctl[C_W4], 2688);

        int wid = tid >> 6, lane = tid & 63;
        int m0 = mt * 16, n0 = nt * 16;
        int row = lane & 15, kg = lane >> 4;

        const u16* pa = cat + (m0 + row) * NCAT + wid * 672 + kg * 8;
        const u16* pb = W4b + (n0 + row) * NCAT + wid * 672 + kg * 8;

        f32x4 acc = {0.f, 0.f, 0.f, 0.f};
        for (int k = 0; k < 672; k += 32)
            acc = __builtin_amdgcn_mfma_f32_16x16x32_bf16(*(const bf16x8*)(pa + k),
                                                          *(const bf16x8*)(pb + k), acc, 0, 0, 0);
        int col = lane & 15, rbase = (lane >> 4) * 4;
        if (wid) {
#pragma unroll
            for (int r = 0; r < 4; ++r) qsf[wid - 1][r][lane] = acc[r];
        }
        __syncthreads();
        if (wid == 0) {
            float bb = b4[n0 + col];
#pragma unroll
            for (int r = 0; r < 4; ++r) {
                float v = acc[r] + qsf[0][r][lane] + qsf[1][r][lane] + qsf[2][r][lane] + bb;
                out2[(m0 + rbase + r) * NFEAT + n0 + col] = fmaxf(v, 0.f);
            }
        }
    }
}

// ---------------------------------------------------------------------------
extern "C" void kernel_launch(void* const* d_in, const int* in_sizes, int n_in,
                              void* d_out, int out_size, void* d_ws, size_t ws_size,
                              hipStream_t stream) {
    (void)in_sizes; (void)n_in; (void)out_size; (void)ws_size;
    const float* vf      = (const float*)d_in[3];
    const float* sen_fea = (const float*)d_in[4];
    const float* loc     = (const float*)d_in[5];
    const int*   vmask   = (const int*)d_in[7];
    const float* W1 = (const float*)d_in[8];
    const float* b1 = (const float*)d_in[9];
    const float* W2 = (const float*)d_in[10];
    const float* b2 = (const float*)d_in[11];
    const float* W3 = (const float*)d_in[12];
    const float* b3 = (const float*)d_in[13];
    const float* W4 = (const float*)d_in[14];
    const float* b4 = (const float*)d_in[15];

    float* out0 = (float*)d_out;
    float* out1 = out0 + (size_t)BS * T * D;
    float* out2 = out1 + (size_t)BS * D;

    char* w = (char*)d_ws;
    int*   ctl  = (int*)w;                                     // 4 KB, zeroed below
    float* pgv  = (float*)(w + 4096);                          // 4 MB
    float* pseg = (float*)(w + 4096 + 4194304);                // 4 MB
    u16*   cat  = (u16*)  (w + 4096 + 2 * 4194304);            // 688128 B
    u16*   lv   = (u16*)  (w + 4096 + 2 * 4194304 + 688128);   // 262144 B
    u16*   W1b  = (u16*)  (w + 4096 + 2 * 4194304 + 950272);   // 1 MB
    u16*   W2b  = (u16*)  (w + 4096 + 2 * 4194304 + 950272 + 1048576);
    u16*   W4b  = (u16*)  (w + 4096 + 2 * 4194304 + 950272 + 2097152);

    hipMemsetAsync(ctl, 0, 4096, stream);
    mega<<<5376, 256, 0, stream>>>(vf, out0, vmask, loc, sen_fea,
                                   W1, W2, W3, W4, b1, b2, b3, b4,
                                   W1b, W2b, W4b, pgv, pseg, cat, lv,
                                   out1, out2, ctl);
}

// Round 5
// 132.558 us; speedup vs baseline: 5.9674x; 5.9674x over previous
//
#include <hip/hip_runtime.h>

#define BS 128
#define T 256
#define D 1024
#define NCAT 2688
#define NFEAT 1024

typedef short bf16x8 __attribute__((ext_vector_type(8)));
typedef float f32x4 __attribute__((ext_vector_type(4)));
typedef unsigned short u16;
typedef u16 u16x4 __attribute__((ext_vector_type(4)));

__device__ __forceinline__ u16 f2bf(float f) {
    unsigned int u = __float_as_uint(f);
    u += 0x7fffu + ((u >> 16) & 1u);   // round-to-nearest-even
    return (u16)(u >> 16);
}

// ctl layout (ints): [0..127] per-batch chunk-done counters (memset 0 each call)
//                    [128..255] vl per batch (written by finalizer, read by L3)

// ---------------------------------------------------------------------------
// L1: blocks [0,1024): copy+pool rows t < vl of batch b (chunk tc of 32 rows);
//     the last-finishing chunk block finalizes the batch (gv/lv -> cat, sen ->
//     cat+out1, loc head) — one-shot agent-scope counter, NO spinning.
//     blocks [1024,4736): f32->bf16 convert of W1, W2, W4.
// cat layout: [sen 0..1023 | gv 1024..2047 | vs 2048..2559 | loc 2560..2687]
// ---------------------------------------------------------------------------
__global__ __launch_bounds__(256, 4)
void kL1(const float* __restrict__ vf, float* __restrict__ out0,
         const int* __restrict__ vmask, const float* __restrict__ loc,
         const float* __restrict__ sen_fea,
         const float* __restrict__ W1, const float* __restrict__ W2,
         const float* __restrict__ W3, const float* __restrict__ W4,
         const float* __restrict__ b3,
         u16* __restrict__ W1b, u16* __restrict__ W2b, u16* __restrict__ W4b,
         float* __restrict__ pgv, float* __restrict__ pseg,
         u16* __restrict__ cat, u16* __restrict__ lv,
         float* __restrict__ out1, int* __restrict__ ctl) {
    int blk = blockIdx.x, tid = threadIdx.x;

    if (blk >= 1024) {                       // ---- weight conversion ----
        int i = (blk - 1024) * 256 + tid;    // float4 index, 950272 total
        const float* src; u16* dst;
        if (i < 131072)      { src = W1 + 4 * i;            dst = W1b + 4 * i; }
        else if (i < 262144) { src = W2 + 4 * (i - 131072); dst = W2b + 4 * (i - 131072); }
        else                 { src = W4 + 4 * (i - 262144); dst = W4b + 4 * (i - 262144); }
        f32x4 v = *(const f32x4*)src;
        u16x4 o;
#pragma unroll
        for (int j = 0; j < 4; ++j) o[j] = f2bf(v[j]);
        *(u16x4*)dst = o;
        return;
    }

    // ---- copy + pool (rows t < vl only) ----
    int b = blk >> 3, tc = blk & 7;
    __shared__ int red[256];
    __shared__ int sse[3];
    __shared__ int lastf;
    red[tid] = vmask[b * T + tid];
    __syncthreads();
    for (int off = 128; off > 0; off >>= 1) {
        if (tid < off) red[tid] += red[tid + off];
        __syncthreads();
    }
    if (tid == 0) {
        int vl = red[0];
        float sc = (float)(vl - 1);
        sse[0] = vl;
        sse[1] = (int)floorf(loc[2 * b] * sc);
        sse[2] = (int)floorf(loc[2 * b + 1] * sc);
    }
    __syncthreads();
    int vl = sse[0], s = sse[1], e = sse[2];
    int nchunk = (vl + 31) >> 5;
    if (tc >= nchunk) return;               // no live rows in this chunk

    int t0 = tc * 32;
    int nrows = vl - t0; if (nrows > 32) nrows = 32;
    int d0 = tid * 4;
    f32x4 g  = {0.f, 0.f, 0.f, 0.f};
    f32x4 sg = {0.f, 0.f, 0.f, 0.f};
    const float* src = vf   + ((size_t)(b * T + t0)) * D + d0;
    float*       dst = out0 + ((size_t)(b * T + t0)) * D + d0;
    for (int i = 0; i < nrows; ++i) {
        f32x4 v = *(const f32x4*)src;
        __builtin_nontemporal_store(v, (f32x4*)dst);
        g += v;                              // t < vl guaranteed
        int t = t0 + i;
        if (t >= s && t <= e) sg += v;
        src += D; dst += D;
    }
    int o = (b * 8 + tc) * D + d0;
    *(f32x4*)(pgv  + o) = g;
    *(f32x4*)(pseg + o) = sg;

    __syncthreads();
    if (tid == 0) {
        int old = __hip_atomic_fetch_add(&ctl[b], 1,
                                         __ATOMIC_ACQ_REL, __HIP_MEMORY_SCOPE_AGENT);
        lastf = (old == nchunk - 1);
    }
    __syncthreads();
    if (!lastf) return;

    // -------- finalize batch b (fixed-order reduce over live chunks) --------
    float inv_vl = 1.0f / (float)vl;
    int cnt = e + 1 - s; if (cnt < 1) cnt = 1;
    float inv_cnt = 1.0f / (float)cnt;
    bool valid = (s <= e);
    for (int d = tid; d < D; d += 256) {
        float gs = 0.f, ss = 0.f;
        for (int c = 0; c < nchunk; ++c) {
            gs += pgv [(b * 8 + c) * D + d];
            ss += pseg[(b * 8 + c) * D + d];
        }
        cat[b * NCAT + 1024 + d] = f2bf(gs * inv_vl);
        lv[b * D + d] = f2bf(valid ? ss * inv_cnt : 0.f);
        float sf = sen_fea[b * D + d];
        cat[b * NCAT + d] = f2bf(sf);
        out1[b * D + d] = sf;
    }
    if (tid < 128) {
        float v = loc[2 * b] * W3[2 * tid] + loc[2 * b + 1] * W3[2 * tid + 1] + b3[tid];
        cat[b * NCAT + 2560 + tid] = f2bf(fmaxf(v, 0.f));
    }
    if (tid == 0) ctl[128 + b] = vl;        // for L3's remainder copy
}

// ---------------------------------------------------------------------------
// k3: vs = relu((lv@W1^T+b1)*(sen@W2^T+b2)) -> cat[2048..2559]
// 256 blocks x 2 waves: wave0 = P chain, wave1 = Q chain, same-lane LDS swap.
// ---------------------------------------------------------------------------
__global__ void k3_vs(const u16* __restrict__ lv, const u16* __restrict__ cat_ro,
                      const u16* __restrict__ W1b, const float* __restrict__ b1,
                      const u16* __restrict__ W2b, const float* __restrict__ b2,
                      u16* __restrict__ cat) {
    int wid = threadIdx.x >> 6, lane = threadIdx.x & 63;
    int mt = blockIdx.x >> 5, nt = blockIdx.x & 31;   // 8 x 32 tiles of 16x16
    int m0 = mt * 16, n0 = nt * 16;
    int row = lane & 15, kg = lane >> 4;

    const u16* pa = (wid == 0) ? (lv + (m0 + row) * D + kg * 8)
                               : (cat_ro + (m0 + row) * NCAT + kg * 8);  // sen cols
    const u16* pb = ((wid == 0) ? W1b : W2b) + (n0 + row) * D + kg * 8;

    f32x4 acc = {0.f, 0.f, 0.f, 0.f};
    for (int k = 0; k < 1024; k += 32)
        acc = __builtin_amdgcn_mfma_f32_16x16x32_bf16(*(const bf16x8*)(pa + k),
                                                      *(const bf16x8*)(pb + k), acc, 0, 0, 0);

    int col = lane & 15, rbase = (lane >> 4) * 4;
    float bb = ((wid == 0) ? b1 : b2)[n0 + col];

    __shared__ float qs[4][64];
    if (wid == 1) {
#pragma unroll
        for (int r = 0; r < 4; ++r) qs[r][lane] = acc[r] + bb;
    }
    __syncthreads();
    if (wid == 0) {
#pragma unroll
        for (int r = 0; r < 4; ++r) {
            float p = acc[r] + bb;
            cat[(m0 + rbase + r) * NCAT + 2048 + n0 + col] = f2bf(fmaxf(p * qs[r][lane], 0.f));
        }
    }
}

// ---------------------------------------------------------------------------
// L3: blocks [0,512): k4 feature GEMM (split-K=4, LDS reduce) -> out2.
//     blocks [512,1536): copy remaining visual_fea rows (t >= vl).
// ---------------------------------------------------------------------------
__global__ __launch_bounds__(256, 4)
void kL3(const float* __restrict__ vf, float* __restrict__ out0,
         const u16* __restrict__ cat, const u16* __restrict__ W4b,
         const float* __restrict__ b4, float* __restrict__ out2,
         const int* __restrict__ ctl) {
    int blk = blockIdx.x, tid = threadIdx.x;
    __shared__ float qsf[3][4][64];

    if (blk < 512) {
        // ---------------- k4 ----------------
        int mt = blk >> 6, nt = blk & 63;
        int wid = tid >> 6, lane = tid & 63;
        int m0 = mt * 16, n0 = nt * 16;
        int row = lane & 15, kg = lane >> 4;

        const u16* pa = cat + (m0 + row) * NCAT + wid * 672 + kg * 8;
        const u16* pb = W4b + (n0 + row) * NCAT + wid * 672 + kg * 8;

        f32x4 acc = {0.f, 0.f, 0.f, 0.f};
        for (int k = 0; k < 672; k += 32)
            acc = __builtin_amdgcn_mfma_f32_16x16x32_bf16(*(const bf16x8*)(pa + k),
                                                          *(const bf16x8*)(pb + k), acc, 0, 0, 0);
        int col = lane & 15, rbase = (lane >> 4) * 4;
        if (wid) {
#pragma unroll
            for (int r = 0; r < 4; ++r) qsf[wid - 1][r][lane] = acc[r];
        }
        __syncthreads();
        if (wid == 0) {
            float bb = b4[n0 + col];
#pragma unroll
            for (int r = 0; r < 4; ++r) {
                float v = acc[r] + qsf[0][r][lane] + qsf[1][r][lane] + qsf[2][r][lane] + bb;
                out2[(m0 + rbase + r) * NFEAT + n0 + col] = fmaxf(v, 0.f);
            }
        }
        return;
    }

    // ---------------- remainder copy: rows t >= vl ----------------
    int bi = blk - 512;
    int b = bi >> 3, tc = bi & 7;
    int vl = ctl[128 + b];                  // written by kL1 finalizer
    int t0 = tc * 32;
    int start = (vl > t0) ? vl : t0;
    int end = t0 + 32;
    if (start >= end) return;

    int d0 = tid * 4;
    const float* src = vf   + ((size_t)(b * T + start)) * D + d0;
    float*       dst = out0 + ((size_t)(b * T + start)) * D + d0;
    for (int t = start; t < end; ++t) {
        f32x4 v = *(const f32x4*)src;
        __builtin_nontemporal_store(v, (f32x4*)dst);
        src += D; dst += D;
    }
}

// ---------------------------------------------------------------------------
extern "C" void kernel_launch(void* const* d_in, const int* in_sizes, int n_in,
                              void* d_out, int out_size, void* d_ws, size_t ws_size,
                              hipStream_t stream) {
    (void)in_sizes; (void)n_in; (void)out_size; (void)ws_size;
    const float* vf      = (const float*)d_in[3];
    const float* sen_fea = (const float*)d_in[4];
    const float* loc     = (const float*)d_in[5];
    const int*   vmask   = (const int*)d_in[7];
    const float* W1 = (const float*)d_in[8];
    const float* b1 = (const float*)d_in[9];
    const float* W2 = (const float*)d_in[10];
    const float* b2 = (const float*)d_in[11];
    const float* W3 = (const float*)d_in[12];
    const float* b3 = (const float*)d_in[13];
    const float* W4 = (const float*)d_in[14];
    const float* b4 = (const float*)d_in[15];

    float* out0 = (float*)d_out;
    float* out1 = out0 + (size_t)BS * T * D;
    float* out2 = out1 + (size_t)BS * D;

    char* w = (char*)d_ws;
    int*   ctl  = (int*)w;                                     // 1 KB
    float* pgv  = (float*)(w + 4096);                          // 4 MB
    float* pseg = (float*)(w + 4096 + 4194304);                // 4 MB
    u16*   cat  = (u16*)  (w + 4096 + 2 * 4194304);            // 688128 B
    u16*   lv   = (u16*)  (w + 4096 + 2 * 4194304 + 688128);   // 262144 B
    u16*   W1b  = (u16*)  (w + 4096 + 2 * 4194304 + 950272);   // 1 MB
    u16*   W2b  = (u16*)  (w + 4096 + 2 * 4194304 + 950272 + 1048576);
    u16*   W4b  = (u16*)  (w + 4096 + 2 * 4194304 + 950272 + 2097152);

    hipMemsetAsync(ctl, 0, 512, stream);    // zero per-batch counters only
    kL1<<<4736, 256, 0, stream>>>(vf, out0, vmask, loc, sen_fea,
                                  W1, W2, W3, W4, b3,
                                  W1b, W2b, W4b, pgv, pseg, cat, lv, out1, ctl);
    k3_vs<<<256, 128, 0, stream>>>(lv, cat, W1b, b1, W2b, b2, cat);
    kL3<<<1536, 256, 0, stream>>>(vf, out0, cat, W4b, b4, out2, ctl);
}

// Round 6
// 121.380 us; speedup vs baseline: 6.5169x; 1.0921x over previous
//
#include <hip/hip_runtime.h>

#define BS 128
#define T 256
#define D 1024
#define NCAT 2688
#define NFEAT 1024

typedef short bf16x8 __attribute__((ext_vector_type(8)));
typedef float f32x4 __attribute__((ext_vector_type(4)));
typedef unsigned short u16;
typedef u16 u16x4 __attribute__((ext_vector_type(4)));

__device__ __forceinline__ u16 f2bf(float f) {
    unsigned int u = __float_as_uint(f);
    u += 0x7fffu + ((u >> 16) & 1u);   // round-to-nearest-even
    return (u16)(u >> 16);
}

// shared-mem mask reduce: returns vl (all threads), needs 256-int LDS buffer
__device__ __forceinline__ int mask_vl(const int* __restrict__ vmask, int b, int tid,
                                       int* red) {
    red[tid] = vmask[b * T + tid];
    __syncthreads();
    for (int off = 128; off > 0; off >>= 1) {
        if (tid < off) red[tid] += red[tid + off];
        __syncthreads();
    }
    return red[0];
}

// copy rows [max(vl,t0), t0+32) of batch b  (dead rows; no pooling needed)
__device__ __forceinline__ void dead_copy(int di, int tid,
                                          const float* __restrict__ vf,
                                          float* __restrict__ out0,
                                          const int* __restrict__ vmask, int* red) {
    int b = di >> 3, tc = di & 7;
    int vl = mask_vl(vmask, b, tid, red);
    int t0 = tc * 32;
    int start = (vl > t0) ? vl : t0;
    int end = t0 + 32;
    if (start >= end) return;
    int d0 = tid * 4;
    const float* src = vf   + ((size_t)(b * T + start)) * D + d0;
    float*       dst = out0 + ((size_t)(b * T + start)) * D + d0;
    for (int t = start; t < end; ++t) {
        f32x4 v = __builtin_nontemporal_load((const f32x4*)src);
        __builtin_nontemporal_store(v, (f32x4*)dst);
        src += D; dst += D;
    }
}

// ---------------------------------------------------------------------------
// ka1: blocks [0,1024): copy+pool LIVE rows (t < vl) of (batch b, chunk tc);
//      blocks [1024,4736): f32->bf16 convert of W1, W2, W4 (backfill).
// No atomics anywhere.
// ---------------------------------------------------------------------------
__global__ __launch_bounds__(256, 4)
void ka1(const float* __restrict__ vf, float* __restrict__ out0,
         const int* __restrict__ vmask, const float* __restrict__ loc,
         const float* __restrict__ W1, const float* __restrict__ W2,
         const float* __restrict__ W4,
         u16* __restrict__ W1b, u16* __restrict__ W2b, u16* __restrict__ W4b,
         float* __restrict__ pgv, float* __restrict__ pseg) {
    int blk = blockIdx.x, tid = threadIdx.x;

    if (blk >= 1024) {                       // ---- weight conversion ----
        int i = (blk - 1024) * 256 + tid;    // float4 index, 950272 total
        const float* src; u16* dst;
        if (i < 131072)      { src = W1 + 4 * i;            dst = W1b + 4 * i; }
        else if (i < 262144) { src = W2 + 4 * (i - 131072); dst = W2b + 4 * (i - 131072); }
        else                 { src = W4 + 4 * (i - 262144); dst = W4b + 4 * (i - 262144); }
        f32x4 v = *(const f32x4*)src;
        u16x4 o;
#pragma unroll
        for (int j = 0; j < 4; ++j) o[j] = f2bf(v[j]);
        *(u16x4*)dst = o;
        return;
    }

    // ---- live-row copy + pool ----
    int b = blk >> 3, tc = blk & 7;
    __shared__ int red[256];
    int vl = mask_vl(vmask, b, tid, red);
    float sc = (float)(vl - 1);
    int s = (int)floorf(loc[2 * b] * sc);
    int e = (int)floorf(loc[2 * b + 1] * sc);

    int nchunk = (vl + 31) >> 5;
    if (tc >= nchunk) return;               // no live rows; k2 reads c<nchunk only

    int t0 = tc * 32;
    int nrows = vl - t0; if (nrows > 32) nrows = 32;
    int d0 = tid * 4;
    f32x4 g  = {0.f, 0.f, 0.f, 0.f};
    f32x4 sg = {0.f, 0.f, 0.f, 0.f};
    const float* src = vf   + ((size_t)(b * T + t0)) * D + d0;
    float*       dst = out0 + ((size_t)(b * T + t0)) * D + d0;
    for (int i = 0; i < nrows; ++i) {
        f32x4 v = __builtin_nontemporal_load((const f32x4*)src);
        __builtin_nontemporal_store(v, (f32x4*)dst);
        g += v;                              // t < vl guaranteed
        int t = t0 + i;
        if (t >= s && t <= e) sg += v;
        src += D; dst += D;
    }
    int o = (b * 8 + tc) * D + d0;
    *(f32x4*)(pgv  + o) = g;                 // regular stores: k2 re-reads these
    *(f32x4*)(pseg + o) = sg;
}

// ---------------------------------------------------------------------------
// kB: blocks [0,128): k2 finalize — reduce partials (fixed order, c<nchunk),
//     build cat[sen|gv|..|loc], lv, out1.
//     blocks [128,352): dead-copy chunks [0,224).
// cat layout: [sen 0..1023 | gv 1024..2047 | vs 2048..2559 | loc 2560..2687]
// ---------------------------------------------------------------------------
__global__ __launch_bounds__(256, 4)
void kB(const float* __restrict__ vf, float* __restrict__ out0,
        const int* __restrict__ vmask, const float* __restrict__ loc,
        const float* __restrict__ sen_fea,
        const float* __restrict__ W3, const float* __restrict__ b3,
        const float* __restrict__ pgv, const float* __restrict__ pseg,
        u16* __restrict__ lv, u16* __restrict__ cat, float* __restrict__ out1) {
    int blk = blockIdx.x, tid = threadIdx.x;
    __shared__ int red[256];

    if (blk >= 128) { dead_copy(blk - 128, tid, vf, out0, vmask, red); return; }

    int b = blk;
    int vl = mask_vl(vmask, b, tid, red);
    float sc = (float)(vl - 1);
    int s = (int)floorf(loc[2 * b] * sc);
    int e = (int)floorf(loc[2 * b + 1] * sc);
    int nchunk = (vl + 31) >> 5;

    float inv_vl = 1.0f / (float)vl;
    int cnt = e + 1 - s; if (cnt < 1) cnt = 1;
    float inv_cnt = 1.0f / (float)cnt;
    bool valid = (s <= e);

    for (int d = tid; d < D; d += 256) {
        float gs = 0.f, ss = 0.f;
        for (int c = 0; c < nchunk; ++c) {
            gs += pgv [(b * 8 + c) * D + d];
            ss += pseg[(b * 8 + c) * D + d];
        }
        cat[b * NCAT + 1024 + d] = f2bf(gs * inv_vl);
        lv[b * D + d] = f2bf(valid ? ss * inv_cnt : 0.f);
        float sf = sen_fea[b * D + d];
        cat[b * NCAT + d] = f2bf(sf);
        out1[b * D + d] = sf;
    }
    if (tid < 128) {
        float v = loc[2 * b] * W3[2 * tid] + loc[2 * b + 1] * W3[2 * tid + 1] + b3[tid];
        cat[b * NCAT + 2560 + tid] = f2bf(fmaxf(v, 0.f));
    }
}

// ---------------------------------------------------------------------------
// kC: blocks [0,128): k3 vs-GEMM — vs = relu((lv@W1^T+b1)*(sen@W2^T+b2)).
//     256 thr: sub = tid>>7 picks 16-col subtile, chain = (tid>>6)&1 picks P/Q.
//     blocks [128,352): dead-copy chunks [224,448).
// ---------------------------------------------------------------------------
__global__ __launch_bounds__(256, 4)
void kC(const float* __restrict__ vf, float* __restrict__ out0,
        const int* __restrict__ vmask,
        const u16* __restrict__ lv, const u16* __restrict__ W1b,
        const float* __restrict__ b1, const u16* __restrict__ W2b,
        const float* __restrict__ b2, u16* __restrict__ cat) {
    int blk = blockIdx.x, tid = threadIdx.x;
    __shared__ int red[256];
    __shared__ float qs[2][4][64];

    if (blk >= 128) { dead_copy(blk - 128 + 224, tid, vf, out0, vmask, red); return; }

    int mt = blk >> 4, ntg = blk & 15;       // 8 x 16 groups of 32 cols
    int sub = tid >> 7, chain = (tid >> 6) & 1, lane = tid & 63;
    int m0 = mt * 16, n0 = ntg * 32 + sub * 16;
    int row = lane & 15, kg = lane >> 4;

    const u16* pa = chain ? (cat + (m0 + row) * NCAT + kg * 8)   // sen cols 0..1023
                          : (lv  + (m0 + row) * D    + kg * 8);
    const u16* pb = (chain ? W2b : W1b) + (n0 + row) * D + kg * 8;

    f32x4 acc = {0.f, 0.f, 0.f, 0.f};
    for (int k = 0; k < 1024; k += 32)
        acc = __builtin_amdgcn_mfma_f32_16x16x32_bf16(*(const bf16x8*)(pa + k),
                                                      *(const bf16x8*)(pb + k), acc, 0, 0, 0);
    int col = lane & 15, rbase = (lane >> 4) * 4;
    float bb = (chain ? b2 : b1)[n0 + col];
    if (chain) {
#pragma unroll
        for (int r = 0; r < 4; ++r) qs[sub][r][lane] = acc[r] + bb;
    }
    __syncthreads();
    if (!chain) {
#pragma unroll
        for (int r = 0; r < 4; ++r) {
            float p = acc[r] + bb;
            cat[(m0 + rbase + r) * NCAT + 2048 + n0 + col] =
                f2bf(fmaxf(p * qs[sub][r][lane], 0.f));
        }
    }
}

// ---------------------------------------------------------------------------
// kD: blocks [0,512): k4 feature GEMM (split-K=4, LDS reduce) -> out2.
//     blocks [512,1088): dead-copy chunks [448,1024).
// ---------------------------------------------------------------------------
__global__ __launch_bounds__(256, 4)
void kD(const float* __restrict__ vf, float* __restrict__ out0,
        const int* __restrict__ vmask,
        const u16* __restrict__ cat, const u16* __restrict__ W4b,
        const float* __restrict__ b4, float* __restrict__ out2) {
    int blk = blockIdx.x, tid = threadIdx.x;
    __shared__ int red[256];
    __shared__ float qsf[3][4][64];

    if (blk >= 512) { dead_copy(blk - 512 + 448, tid, vf, out0, vmask, red); return; }

    int mt = blk >> 6, nt = blk & 63;
    int wid = tid >> 6, lane = tid & 63;
    int m0 = mt * 16, n0 = nt * 16;
    int row = lane & 15, kg = lane >> 4;

    const u16* pa = cat + (m0 + row) * NCAT + wid * 672 + kg * 8;
    const u16* pb = W4b + (n0 + row) * NCAT + wid * 672 + kg * 8;

    f32x4 acc = {0.f, 0.f, 0.f, 0.f};
    for (int k = 0; k < 672; k += 32)
        acc = __builtin_amdgcn_mfma_f32_16x16x32_bf16(*(const bf16x8*)(pa + k),
                                                      *(const bf16x8*)(pb + k), acc, 0, 0, 0);
    int col = lane & 15, rbase = (lane >> 4) * 4;
    if (wid) {
#pragma unroll
        for (int r = 0; r < 4; ++r) qsf[wid - 1][r][lane] = acc[r];
    }
    __syncthreads();
    if (wid == 0) {
        float bb = b4[n0 + col];
#pragma unroll
        for (int r = 0; r < 4; ++r) {
            float v = acc[r] + qsf[0][r][lane] + qsf[1][r][lane] + qsf[2][r][lane] + bb;
            out2[(m0 + rbase + r) * NFEAT + n0 + col] = fmaxf(v, 0.f);
        }
    }
}

// ---------------------------------------------------------------------------
extern "C" void kernel_launch(void* const* d_in, const int* in_sizes, int n_in,
                              void* d_out, int out_size, void* d_ws, size_t ws_size,
                              hipStream_t stream) {
    (void)in_sizes; (void)n_in; (void)out_size; (void)ws_size;
    const float* vf      = (const float*)d_in[3];
    const float* sen_fea = (const float*)d_in[4];
    const float* loc     = (const float*)d_in[5];
    const int*   vmask   = (const int*)d_in[7];
    const float* W1 = (const float*)d_in[8];
    const float* b1 = (const float*)d_in[9];
    const float* W2 = (const float*)d_in[10];
    const float* b2 = (const float*)d_in[11];
    const float* W3 = (const float*)d_in[12];
    const float* b3 = (const float*)d_in[13];
    const float* W4 = (const float*)d_in[14];
    const float* b4 = (const float*)d_in[15];

    float* out0 = (float*)d_out;
    float* out1 = out0 + (size_t)BS * T * D;
    float* out2 = out1 + (size_t)BS * D;

    char* w = (char*)d_ws;
    float* pgv  = (float*)(w);                                // 4 MB
    float* pseg = (float*)(w + 4194304);                      // 4 MB
    u16*   cat  = (u16*)  (w + 2 * 4194304);                  // 688128 B
    u16*   lv   = (u16*)  (w + 2 * 4194304 + 688128);         // 262144 B
    u16*   W1b  = (u16*)  (w + 2 * 4194304 + 950272);         // 1 MB
    u16*   W2b  = (u16*)  (w + 2 * 4194304 + 950272 + 1048576);
    u16*   W4b  = (u16*)  (w + 2 * 4194304 + 950272 + 2097152);  // 5.25 MB

    ka1<<<4736, 256, 0, stream>>>(vf, out0, vmask, loc, W1, W2, W4,
                                  W1b, W2b, W4b, pgv, pseg);
    kB<<<352, 256, 0, stream>>>(vf, out0, vmask, loc, sen_fea, W3, b3,
                                pgv, pseg, lv, cat, out1);
    kC<<<352, 256, 0, stream>>>(vf, out0, vmask, lv, W1b, b1, W2b, b2, cat);
    kD<<<1088, 256, 0, stream>>>(vf, out0, vmask, cat, W4b, b4, out2);
}

// Round 7
// 89.026 us; speedup vs baseline: 8.8853x; 1.3634x over previous
//
#include <hip/hip_runtime.h>

#define BS 128
#define T 256
#define D 1024
#define NCAT 2688
#define NFEAT 1024

typedef short bf16x8 __attribute__((ext_vector_type(8)));
typedef float f32x4 __attribute__((ext_vector_type(4)));
typedef unsigned short u16;
typedef u16 u16x4 __attribute__((ext_vector_type(4)));

__device__ __forceinline__ u16 f2bf(float f) {
    unsigned int u = __float_as_uint(f);
    u += 0x7fffu + ((u >> 16) & 1u);   // round-to-nearest-even
    return (u16)(u >> 16);
}

// ---------------------------------------------------------------------------
// ka: blocks [0,1024): (b,tc) — POOL all 32 rows (fixed loop, predicated acc);
//     COPY to out0 only for tc<4 (rows 0..127). Rows 128..255 copied in kD.
//     blocks [1024,4736): f32->bf16 convert of W1, W2, W4 (backfill).
// All loops compile-time bound (MLP!). Regular loads (keep vf in L3 for kD).
// ---------------------------------------------------------------------------
__global__ __launch_bounds__(256, 4)
void ka(const float* __restrict__ vf, float* __restrict__ out0,
        const int* __restrict__ vmask, const float* __restrict__ loc,
        const float* __restrict__ W1, const float* __restrict__ W2,
        const float* __restrict__ W4,
        u16* __restrict__ W1b, u16* __restrict__ W2b, u16* __restrict__ W4b,
        float* __restrict__ pgv, float* __restrict__ pseg) {
    int blk = blockIdx.x, tid = threadIdx.x;

    if (blk >= 1024) {                       // ---- weight conversion ----
        int i = (blk - 1024) * 256 + tid;    // float4 index, 950272 total
        const float* src; u16* dst;
        if (i < 131072)      { src = W1 + 4 * i;            dst = W1b + 4 * i; }
        else if (i < 262144) { src = W2 + 4 * (i - 131072); dst = W2b + 4 * (i - 131072); }
        else                 { src = W4 + 4 * (i - 262144); dst = W4b + 4 * (i - 262144); }
        f32x4 v = *(const f32x4*)src;
        u16x4 o;
#pragma unroll
        for (int j = 0; j < 4; ++j) o[j] = f2bf(v[j]);
        *(u16x4*)dst = o;
        return;
    }

    // ---- pool (+copy if tc<4), fixed 32-iteration loops ----
    int b = blk >> 3, tc = blk & 7;
    __shared__ int red[256];
    __shared__ int sse[3];
    red[tid] = vmask[b * T + tid];
    __syncthreads();
    for (int off = 128; off > 0; off >>= 1) {
        if (tid < off) red[tid] += red[tid + off];
        __syncthreads();
    }
    if (tid == 0) {
        int vl = red[0];
        float sc = (float)(vl - 1);
        sse[0] = vl;
        sse[1] = (int)floorf(loc[2 * b] * sc);
        sse[2] = (int)floorf(loc[2 * b + 1] * sc);
    }
    __syncthreads();
    int vl = sse[0], s = sse[1], e = sse[2];

    int t0 = tc * 32;
    int d0 = tid * 4;
    f32x4 g  = {0.f, 0.f, 0.f, 0.f};
    f32x4 sg = {0.f, 0.f, 0.f, 0.f};
    const float* src = vf   + ((size_t)(b * T + t0)) * D + d0;
    float*       dst = out0 + ((size_t)(b * T + t0)) * D + d0;

    if (tc < 4) {
        for (int i = 0; i < 32; ++i) {       // fixed bound -> unrolled, deep MLP
            f32x4 v = *(const f32x4*)src;
            __builtin_nontemporal_store(v, (f32x4*)dst);
            int t = t0 + i;
            if (t < vl) g += v;
            if (t >= s && t <= e) sg += v;
            src += D; dst += D;
        }
    } else {
        for (int i = 0; i < 32; ++i) {       // pool only; copy deferred to kD
            f32x4 v = *(const f32x4*)src;
            int t = t0 + i;
            if (t < vl) g += v;
            if (t >= s && t <= e) sg += v;
            src += D;
        }
    }
    int o = (b * 8 + tc) * D + d0;
    *(f32x4*)(pgv  + o) = g;
    *(f32x4*)(pseg + o) = sg;
}

// ---------------------------------------------------------------------------
// k2: reduce partials -> gv_fea / lv_fea; build cat + out1; loc_fea head.
// cat layout: [sen 0..1023 | gv 1024..2047 | vs 2048..2559 | loc 2560..2687]
// ---------------------------------------------------------------------------
__global__ void k2_build(const float* __restrict__ sen_fea, const float* __restrict__ loc,
                         const float* __restrict__ W3, const float* __restrict__ b3,
                         const int* __restrict__ vmask,
                         const float* __restrict__ pgv, const float* __restrict__ pseg,
                         u16* __restrict__ lv_bf, u16* __restrict__ cat,
                         float* __restrict__ out1) {
    int b = blockIdx.x, tid = threadIdx.x;   // 128 x 256
    __shared__ int red[256];
    __shared__ int sse[3];
    red[tid] = vmask[b * T + tid];
    __syncthreads();
    for (int off = 128; off > 0; off >>= 1) {
        if (tid < off) red[tid] += red[tid + off];
        __syncthreads();
    }
    if (tid == 0) {
        int vl = red[0];
        float sc = (float)(vl - 1);
        sse[0] = vl;
        sse[1] = (int)floorf(loc[2 * b] * sc);
        sse[2] = (int)floorf(loc[2 * b + 1] * sc);
    }
    __syncthreads();
    int vl = sse[0], s = sse[1], e = sse[2];

    float inv_vl = 1.0f / (float)vl;
    int cnt = e + 1 - s; if (cnt < 1) cnt = 1;
    float inv_cnt = 1.0f / (float)cnt;
    bool valid = (s <= e);

    for (int d = tid; d < D; d += 256) {
        float gs = 0.f, ss = 0.f;
#pragma unroll
        for (int c = 0; c < 8; ++c) {
            gs += pgv [(b * 8 + c) * D + d];
            ss += pseg[(b * 8 + c) * D + d];
        }
        cat[b * NCAT + 1024 + d] = f2bf(gs * inv_vl);
        lv_bf[b * D + d] = f2bf(valid ? ss * inv_cnt : 0.f);
        float sf = sen_fea[b * D + d];
        cat[b * NCAT + d] = f2bf(sf);
        out1[b * D + d] = sf;
    }
    if (tid < 128) {
        float v = loc[2 * b] * W3[2 * tid] + loc[2 * b + 1] * W3[2 * tid + 1] + b3[tid];
        cat[b * NCAT + 2560 + tid] = f2bf(fmaxf(v, 0.f));
    }
}

// ---------------------------------------------------------------------------
// k3: vs = relu((lv@W1^T+b1)*(sen@W2^T+b2)) -> cat[2048..2559]
// 256 blocks x 2 waves: wave0 = P chain, wave1 = Q chain, same-lane LDS swap.
// ---------------------------------------------------------------------------
__global__ void k3_vs(const u16* __restrict__ lv, const u16* __restrict__ cat_ro,
                      const u16* __restrict__ W1b, const float* __restrict__ b1,
                      const u16* __restrict__ W2b, const float* __restrict__ b2,
                      u16* __restrict__ cat) {
    int wid = threadIdx.x >> 6, lane = threadIdx.x & 63;
    int mt = blockIdx.x >> 5, nt = blockIdx.x & 31;   // 8 x 32 tiles of 16x16
    int m0 = mt * 16, n0 = nt * 16;
    int row = lane & 15, kg = lane >> 4;

    const u16* pa = (wid == 0) ? (lv + (m0 + row) * D + kg * 8)
                               : (cat_ro + (m0 + row) * NCAT + kg * 8);  // sen cols
    const u16* pb = ((wid == 0) ? W1b : W2b) + (n0 + row) * D + kg * 8;

    f32x4 acc = {0.f, 0.f, 0.f, 0.f};
    for (int k = 0; k < 1024; k += 32)
        acc = __builtin_amdgcn_mfma_f32_16x16x32_bf16(*(const bf16x8*)(pa + k),
                                                      *(const bf16x8*)(pb + k), acc, 0, 0, 0);

    int col = lane & 15, rbase = (lane >> 4) * 4;
    float bb = ((wid == 0) ? b1 : b2)[n0 + col];

    __shared__ float qs[4][64];
    if (wid == 1) {
#pragma unroll
        for (int r = 0; r < 4; ++r) qs[r][lane] = acc[r] + bb;
    }
    __syncthreads();
    if (wid == 0) {
#pragma unroll
        for (int r = 0; r < 4; ++r) {
            float p = acc[r] + bb;
            cat[(m0 + rbase + r) * NCAT + 2048 + n0 + col] = f2bf(fmaxf(p * qs[r][lane], 0.f));
        }
    }
}

// ---------------------------------------------------------------------------
// kD: blocks [0,512): k4 feature GEMM (split-K=4, LDS reduce) -> out2.
//     blocks [512,1024): copy visual_fea rows [128,256) -> out0 (no vl logic;
//     fixed 32-row unrolled chunks). 1024 blocks = 4/CU co-resident.
// ---------------------------------------------------------------------------
__global__ __launch_bounds__(256, 4)
void kD(const float* __restrict__ vf, float* __restrict__ out0,
        const u16* __restrict__ cat, const u16* __restrict__ W4b,
        const float* __restrict__ b4, float* __restrict__ out2) {
    int blk = blockIdx.x, tid = threadIdx.x;
    __shared__ float qsf[3][4][64];

    if (blk >= 512) {
        // ---- copy rows [128,256): chunk ci -> (b, tc=4+(ci&3)) ----
        int ci = blk - 512;
        int b = ci >> 2, tc = 4 + (ci & 3);
        int t0 = tc * 32;
        int d0 = tid * 4;
        const float* src = vf   + ((size_t)(b * T + t0)) * D + d0;
        float*       dst = out0 + ((size_t)(b * T + t0)) * D + d0;
        for (int i = 0; i < 32; ++i) {       // fixed bound -> unrolled, deep MLP
            f32x4 v = *(const f32x4*)src;
            __builtin_nontemporal_store(v, (f32x4*)dst);
            src += D; dst += D;
        }
        return;
    }

    // ---- k4: split-K=4, LDS reduce ----
    int mt = blk >> 6, nt = blk & 63;
    int wid = tid >> 6, lane = tid & 63;
    int m0 = mt * 16, n0 = nt * 16;
    int row = lane & 15, kg = lane >> 4;

    const u16* pa = cat + (m0 + row) * NCAT + wid * 672 + kg * 8;
    const u16* pb = W4b + (n0 + row) * NCAT + wid * 672 + kg * 8;

    f32x4 acc = {0.f, 0.f, 0.f, 0.f};
    for (int k = 0; k < 672; k += 32)
        acc = __builtin_amdgcn_mfma_f32_16x16x32_bf16(*(const bf16x8*)(pa + k),
                                                      *(const bf16x8*)(pb + k), acc, 0, 0, 0);
    int col = lane & 15, rbase = (lane >> 4) * 4;
    if (wid) {
#pragma unroll
        for (int r = 0; r < 4; ++r) qsf[wid - 1][r][lane] = acc[r];
    }
    __syncthreads();
    if (wid == 0) {
        float bb = b4[n0 + col];
#pragma unroll
        for (int r = 0; r < 4; ++r) {
            float v = acc[r] + qsf[0][r][lane] + qsf[1][r][lane] + qsf[2][r][lane] + bb;
            out2[(m0 + rbase + r) * NFEAT + n0 + col] = fmaxf(v, 0.f);
        }
    }
}

// ---------------------------------------------------------------------------
extern "C" void kernel_launch(void* const* d_in, const int* in_sizes, int n_in,
                              void* d_out, int out_size, void* d_ws, size_t ws_size,
                              hipStream_t stream) {
    (void)in_sizes; (void)n_in; (void)out_size; (void)ws_size;
    const float* vf      = (const float*)d_in[3];
    const float* sen_fea = (const float*)d_in[4];
    const float* loc     = (const float*)d_in[5];
    const int*   vmask   = (const int*)d_in[7];
    const float* W1 = (const float*)d_in[8];
    const float* b1 = (const float*)d_in[9];
    const float* W2 = (const float*)d_in[10];
    const float* b2 = (const float*)d_in[11];
    const float* W3 = (const float*)d_in[12];
    const float* b3 = (const float*)d_in[13];
    const float* W4 = (const float*)d_in[14];
    const float* b4 = (const float*)d_in[15];

    float* out0 = (float*)d_out;
    float* out1 = out0 + (size_t)BS * T * D;
    float* out2 = out1 + (size_t)BS * D;

    char* w = (char*)d_ws;
    float* pgv  = (float*)(w);                                // 4 MB
    float* pseg = (float*)(w + 4194304);                      // 4 MB
    u16*   cat  = (u16*)  (w + 2 * 4194304);                  // 688128 B
    u16*   lv   = (u16*)  (w + 2 * 4194304 + 688128);         // 262144 B
    u16*   W1b  = (u16*)  (w + 2 * 4194304 + 950272);         // 1 MB
    u16*   W2b  = (u16*)  (w + 2 * 4194304 + 950272 + 1048576);
    u16*   W4b  = (u16*)  (w + 2 * 4194304 + 950272 + 2097152);  // 5.25 MB

    ka<<<4736, 256, 0, stream>>>(vf, out0, vmask, loc, W1, W2, W4,
                                 W1b, W2b, W4b, pgv, pseg);
    k2_build<<<BS, 256, 0, stream>>>(sen_fea, loc, W3, b3, vmask, pgv, pseg, lv, cat, out1);
    k3_vs<<<256, 128, 0, stream>>>(lv, cat, W1b, b1, W2b, b2, cat);
    kD<<<1024, 256, 0, stream>>>(vf, out0, cat, W4b, b4, out2);
}